// Round 2
// baseline (190.778 us; speedup 1.0000x reference)
//
#include <hip/hip_runtime.h>

// Problem constants (PARTViT pairwise head)
#define BB 64
#define NN 576
#define DD 768
#define KK 1024
#define ROWS (BB * NN)    // 36864 patch rows
#define PAIRS (BB * KK)   // 65536 pairs
// d_out layout: [PAIRS*2] f32 head output, then [PAIRS*2] f32 echoed indices
//
// R5: single kernel, manual grid barrier.
// R4 post-mortem: per-CU streaming BW caps at ~27 GB/s (R4 fused: 26 GB/s/CU
// on 64 CUs; harness fills: 26.9; m13 copy: 24.6). So the 113 MB z read MUST
// spread over ~256 CUs with zero redundancy -> grid-wide producer/consumer
// dependency. Cooperative launch silently fails under graph capture (R3), so
// we use a manual arrival-counter barrier in a NORMAL launch:
//   - grid = 256 blocks = #CUs, 512 thr -> co-residency guaranteed
//   - monotonic __device__ counter, never reset (graph-replay-safe):
//     target = (old & ~255) + 256 per round
//   - __threadfence() release/acquire around it for cross-XCD g_P visibility
//     (per-XCD L2s are non-coherent; fence emits wbl2/inv on gfx950)
//   - bounded spin (s_sleep backoff): a residency surprise degrades to a
//     clean absmax failure, not a hang.
// Phase 1: block g projects rows [g*144, (g+1)*144) -> g_P (wave-per-row,
// register weights, 64-lane butterfly; proven R2/R4 body).
// Phase 2: block g resolves pairs [g*256, (g+1)*256) from g_P (L3-resident).

#define NBLK 256
#define TPB  512
#define ROWS_PER_BLK (ROWS / NBLK)            // 144
#define ROWS_PER_WAVE (ROWS_PER_BLK / (TPB/64))  // 18
#define PAIRS_PER_BLK (PAIRS / NBLK)          // 256

__device__ float4   g_P[ROWS];   // per-row projections (rewritten each replay)
__device__ unsigned g_ctr = 0;   // monotonic arrival counter (NEVER reset)

__global__ __launch_bounds__(TPB)
void partvit_onekernel(const float* __restrict__ z,
                       const int* __restrict__ idx,
                       const float* __restrict__ W,
                       const float* __restrict__ bh,
                       float* __restrict__ out) {
    const int lane = threadIdx.x & 63;
    const int wave = threadIdx.x >> 6;   // 0..7

    // ---- Phase 1: projection table ----
    // W is [1536,2] row-major: W[d,t] at 2*d+t -> float2 per d.
    // Lane l owns d = j*256 + 4l + c (j=0..2, c=0..3) of each half.
    const float2* __restrict__ W2 = (const float2*)W;
    float2 wa[3][4], wb[3][4];
#pragma unroll
    for (int j = 0; j < 3; ++j) {
#pragma unroll
        for (int c = 0; c < 4; ++c) {
            const int d = j * 256 + (lane << 2) + c;
            wa[j][c] = W2[d];        // first-half weights (patch-0 slot)
            wb[j][c] = W2[d + DD];   // second-half weights (patch-1 slot)
        }
    }

    const float4* __restrict__ z4 = (const float4*)z;  // 192 float4 per row
    const int rbase = blockIdx.x * ROWS_PER_BLK + wave * ROWS_PER_WAVE;

    // 18 contiguous rows per wave; 2-row unroll keeps 6 dwordx4 in flight.
#pragma unroll 1
    for (int i = 0; i < ROWS_PER_WAVE; i += 2) {
        const int r  = rbase + i;
        const int r2 = r + 1;
        float4 v0[3], v1[3];
#pragma unroll
        for (int j = 0; j < 3; ++j) v0[j] = z4[r  * 192 + j * 64 + lane];
#pragma unroll
        for (int j = 0; j < 3; ++j) v1[j] = z4[r2 * 192 + j * 64 + lane];

        float a00 = 0.f, a01 = 0.f, a10 = 0.f, a11 = 0.f;
        float c00 = 0.f, c01 = 0.f, c10 = 0.f, c11 = 0.f;
#pragma unroll
        for (int j = 0; j < 3; ++j) {
            a00 = fmaf(v0[j].x, wa[j][0].x, a00);
            a00 = fmaf(v0[j].y, wa[j][1].x, a00);
            a00 = fmaf(v0[j].z, wa[j][2].x, a00);
            a00 = fmaf(v0[j].w, wa[j][3].x, a00);
            a01 = fmaf(v0[j].x, wa[j][0].y, a01);
            a01 = fmaf(v0[j].y, wa[j][1].y, a01);
            a01 = fmaf(v0[j].z, wa[j][2].y, a01);
            a01 = fmaf(v0[j].w, wa[j][3].y, a01);
            a10 = fmaf(v0[j].x, wb[j][0].x, a10);
            a10 = fmaf(v0[j].y, wb[j][1].x, a10);
            a10 = fmaf(v0[j].z, wb[j][2].x, a10);
            a10 = fmaf(v0[j].w, wb[j][3].x, a10);
            a11 = fmaf(v0[j].x, wb[j][0].y, a11);
            a11 = fmaf(v0[j].y, wb[j][1].y, a11);
            a11 = fmaf(v0[j].z, wb[j][2].y, a11);
            a11 = fmaf(v0[j].w, wb[j][3].y, a11);

            c00 = fmaf(v1[j].x, wa[j][0].x, c00);
            c00 = fmaf(v1[j].y, wa[j][1].x, c00);
            c00 = fmaf(v1[j].z, wa[j][2].x, c00);
            c00 = fmaf(v1[j].w, wa[j][3].x, c00);
            c01 = fmaf(v1[j].x, wa[j][0].y, c01);
            c01 = fmaf(v1[j].y, wa[j][1].y, c01);
            c01 = fmaf(v1[j].z, wa[j][2].y, c01);
            c01 = fmaf(v1[j].w, wa[j][3].y, c01);
            c10 = fmaf(v1[j].x, wb[j][0].x, c10);
            c10 = fmaf(v1[j].y, wb[j][1].x, c10);
            c10 = fmaf(v1[j].z, wb[j][2].x, c10);
            c10 = fmaf(v1[j].w, wb[j][3].x, c10);
            c11 = fmaf(v1[j].x, wb[j][0].y, c11);
            c11 = fmaf(v1[j].y, wb[j][1].y, c11);
            c11 = fmaf(v1[j].z, wb[j][2].y, c11);
            c11 = fmaf(v1[j].w, wb[j][3].y, c11);
        }
#pragma unroll
        for (int off = 32; off > 0; off >>= 1) {
            a00 += __shfl_xor(a00, off, 64);
            a01 += __shfl_xor(a01, off, 64);
            a10 += __shfl_xor(a10, off, 64);
            a11 += __shfl_xor(a11, off, 64);
            c00 += __shfl_xor(c00, off, 64);
            c01 += __shfl_xor(c01, off, 64);
            c10 += __shfl_xor(c10, off, 64);
            c11 += __shfl_xor(c11, off, 64);
        }
        if (lane == 0) {
            g_P[r]  = make_float4(a00, a01, a10, a11);
            g_P[r2] = make_float4(c00, c01, c10, c11);
        }
    }

    // ---- Grid barrier (manual, replay-safe) ----
    __syncthreads();
    if (threadIdx.x == 0) {
        __threadfence();  // release: this block's g_P stores visible agent-wide
        const unsigned old = atomicAdd(&g_ctr, 1u);           // device scope
        const unsigned target = (old & ~255u) + 256u;         // this round's goal
        int spins = 0;
        while (__hip_atomic_load(&g_ctr, __ATOMIC_RELAXED,
                                 __HIP_MEMORY_SCOPE_AGENT) < target) {
            if (++spins > (1 << 18)) break;  // ~ms-scale bailout: clean fail, no hang
            __builtin_amdgcn_s_sleep(2);
        }
        __threadfence();  // acquire: invalidate L1/L2 so g_P reads are fresh
    }
    __syncthreads();

    // ---- Phase 2: 256 pairs for this block ----
    if (threadIdx.x < PAIRS_PER_BLK) {
        const int t = blockIdx.x * PAIRS_PER_BLK + (int)threadIdx.x;  // b*K + k
        const int2 id = ((const int2*)idx)[t];
        const int i0 = min(max(id.x, 0), NN - 1);   // clamp: dtype surprise ->
        const int i1 = min(max(id.y, 0), NN - 1);   // absmax fail, not a fault
        const int b = t >> 10;  // K = 1024
        const float4 p0 = g_P[b * NN + i0];
        const float4 p1 = g_P[b * NN + i1];
        const float b0 = bh[0], b1 = bh[1];
        ((float2*)out)[t] = make_float2(p0.x + p1.z + b0, p0.y + p1.w + b1);
        ((float2*)out)[PAIRS + t] = make_float2((float)id.x, (float)id.y);
    }
}

extern "C" void kernel_launch(void* const* d_in, const int* in_sizes, int n_in,
                              void* d_out, int out_size, void* d_ws, size_t ws_size,
                              hipStream_t stream) {
    const float* z   = (const float*)d_in[0];
    const int*   idx = (const int*)d_in[1];
    const float* W   = (const float*)d_in[2];
    const float* bh  = (const float*)d_in[3];
    float*       out = (float*)d_out;
    (void)d_ws; (void)ws_size; (void)in_sizes; (void)n_in; (void)out_size;

    // 256 blocks = #CUs (manual-barrier residency guarantee), 8 waves each.
    partvit_onekernel<<<NBLK, TPB, 0, stream>>>(z, idx, W, bh, out);
}

// Round 3
// 187.974 us; speedup vs baseline: 1.0149x; 1.0149x over previous
//
#include <hip/hip_runtime.h>

// Problem constants (PARTViT pairwise head)
#define BB 64
#define NN 576
#define DD 768
#define KK 1024
#define ROWS (BB * NN)    // 36864 patch rows
#define PAIRS (BB * KK)   // 65536 pairs
// d_out layout: [PAIRS*2] f32 head output, then [PAIRS*2] f32 echoed indices
//
// R6: same single-kernel manual-barrier structure as R5; fix the two R5
// pathologies the counters exposed:
//   - VGPR_Count=40 -> compiler was RELOADING the 48-reg weight set every
//     iteration (launch_bounds gave it no budget). Now __launch_bounds__
//     (1024,4): 4 waves/SIMD min -> 128-VGPR cap, weights stay resident.
//   - Occupancy 21% (2 waves/SIMD) -> latency-bound at 6.8 GB/s/CU vs the
//     ~27 GB/s/CU streaming cap (R4/fills/m13 all agree on ~25-27). Now
//     1024 thr/block = 16 waves/CU, 9 rows/wave with 3-row unroll = 9 KB
//     loads in flight per wave.
//   - idx prefetched BEFORE the barrier (independent of g_P).
// Barrier: monotonic counter, never reset (graph-replay-safe), release/
// acquire fences for cross-XCD g_P visibility, bounded spin (clean absmax
// failure instead of hang if co-residency ever breaks).

#define NBLK 256
#define TPB  1024
#define WAVES (TPB / 64)                      // 16
#define ROWS_PER_BLK (ROWS / NBLK)            // 144
#define ROWS_PER_WAVE (ROWS_PER_BLK / WAVES)  // 9
#define PAIRS_PER_BLK (PAIRS / NBLK)          // 256

__device__ float4   g_P[ROWS];   // per-row projections (rewritten each replay)
__device__ unsigned g_ctr = 0;   // monotonic arrival counter (NEVER reset)

__global__ __launch_bounds__(TPB, 4)
void partvit_onekernel(const float* __restrict__ z,
                       const int* __restrict__ idx,
                       const float* __restrict__ W,
                       const float* __restrict__ bh,
                       float* __restrict__ out) {
    const int lane = threadIdx.x & 63;
    const int wave = threadIdx.x >> 6;   // 0..15

    // ---- Prefetch this thread's pair index (independent of g_P) ----
    int2 id = make_int2(0, 0);
    const int ptid = (int)threadIdx.x;
    if (ptid < PAIRS_PER_BLK) {
        id = ((const int2*)idx)[blockIdx.x * PAIRS_PER_BLK + ptid];
    }

    // ---- Phase 1: projection table ----
    // W is [1536,2] row-major: W[d,t] at 2*d+t -> float2 per d.
    // Lane l owns d = j*256 + 4l + c (j=0..2, c=0..3) of each half.
    const float2* __restrict__ W2 = (const float2*)W;
    float2 wa[3][4], wb[3][4];
#pragma unroll
    for (int j = 0; j < 3; ++j) {
#pragma unroll
        for (int c = 0; c < 4; ++c) {
            const int d = j * 256 + (lane << 2) + c;
            wa[j][c] = W2[d];        // first-half weights (patch-0 slot)
            wb[j][c] = W2[d + DD];   // second-half weights (patch-1 slot)
        }
    }

    const float4* __restrict__ z4 = (const float4*)z;  // 192 float4 per row
    const int rbase = blockIdx.x * ROWS_PER_BLK + wave * ROWS_PER_WAVE;

    // 9 contiguous rows per wave; 3-row unroll keeps 9 dwordx4 (9 KB) in
    // flight per wave before the FMA/reduce block.
#pragma unroll 1
    for (int i = 0; i < ROWS_PER_WAVE; i += 3) {
        const int r0 = rbase + i;
        float4 v0[3], v1[3], v2[3];
#pragma unroll
        for (int j = 0; j < 3; ++j) v0[j] = z4[(r0    ) * 192 + j * 64 + lane];
#pragma unroll
        for (int j = 0; j < 3; ++j) v1[j] = z4[(r0 + 1) * 192 + j * 64 + lane];
#pragma unroll
        for (int j = 0; j < 3; ++j) v2[j] = z4[(r0 + 2) * 192 + j * 64 + lane];

        float a00 = 0.f, a01 = 0.f, a10 = 0.f, a11 = 0.f;
        float c00 = 0.f, c01 = 0.f, c10 = 0.f, c11 = 0.f;
        float e00 = 0.f, e01 = 0.f, e10 = 0.f, e11 = 0.f;
#pragma unroll
        for (int j = 0; j < 3; ++j) {
            a00 = fmaf(v0[j].x, wa[j][0].x, a00);
            a00 = fmaf(v0[j].y, wa[j][1].x, a00);
            a00 = fmaf(v0[j].z, wa[j][2].x, a00);
            a00 = fmaf(v0[j].w, wa[j][3].x, a00);
            a01 = fmaf(v0[j].x, wa[j][0].y, a01);
            a01 = fmaf(v0[j].y, wa[j][1].y, a01);
            a01 = fmaf(v0[j].z, wa[j][2].y, a01);
            a01 = fmaf(v0[j].w, wa[j][3].y, a01);
            a10 = fmaf(v0[j].x, wb[j][0].x, a10);
            a10 = fmaf(v0[j].y, wb[j][1].x, a10);
            a10 = fmaf(v0[j].z, wb[j][2].x, a10);
            a10 = fmaf(v0[j].w, wb[j][3].x, a10);
            a11 = fmaf(v0[j].x, wb[j][0].y, a11);
            a11 = fmaf(v0[j].y, wb[j][1].y, a11);
            a11 = fmaf(v0[j].z, wb[j][2].y, a11);
            a11 = fmaf(v0[j].w, wb[j][3].y, a11);

            c00 = fmaf(v1[j].x, wa[j][0].x, c00);
            c00 = fmaf(v1[j].y, wa[j][1].x, c00);
            c00 = fmaf(v1[j].z, wa[j][2].x, c00);
            c00 = fmaf(v1[j].w, wa[j][3].x, c00);
            c01 = fmaf(v1[j].x, wa[j][0].y, c01);
            c01 = fmaf(v1[j].y, wa[j][1].y, c01);
            c01 = fmaf(v1[j].z, wa[j][2].y, c01);
            c01 = fmaf(v1[j].w, wa[j][3].y, c01);
            c10 = fmaf(v1[j].x, wb[j][0].x, c10);
            c10 = fmaf(v1[j].y, wb[j][1].x, c10);
            c10 = fmaf(v1[j].z, wb[j][2].x, c10);
            c10 = fmaf(v1[j].w, wb[j][3].x, c10);
            c11 = fmaf(v1[j].x, wb[j][0].y, c11);
            c11 = fmaf(v1[j].y, wb[j][1].y, c11);
            c11 = fmaf(v1[j].z, wb[j][2].y, c11);
            c11 = fmaf(v1[j].w, wb[j][3].y, c11);

            e00 = fmaf(v2[j].x, wa[j][0].x, e00);
            e00 = fmaf(v2[j].y, wa[j][1].x, e00);
            e00 = fmaf(v2[j].z, wa[j][2].x, e00);
            e00 = fmaf(v2[j].w, wa[j][3].x, e00);
            e01 = fmaf(v2[j].x, wa[j][0].y, e01);
            e01 = fmaf(v2[j].y, wa[j][1].y, e01);
            e01 = fmaf(v2[j].z, wa[j][2].y, e01);
            e01 = fmaf(v2[j].w, wa[j][3].y, e01);
            e10 = fmaf(v2[j].x, wb[j][0].x, e10);
            e10 = fmaf(v2[j].y, wb[j][1].x, e10);
            e10 = fmaf(v2[j].z, wb[j][2].x, e10);
            e10 = fmaf(v2[j].w, wb[j][3].x, e10);
            e11 = fmaf(v2[j].x, wb[j][0].y, e11);
            e11 = fmaf(v2[j].y, wb[j][1].y, e11);
            e11 = fmaf(v2[j].z, wb[j][2].y, e11);
            e11 = fmaf(v2[j].w, wb[j][3].y, e11);
        }
#pragma unroll
        for (int off = 32; off > 0; off >>= 1) {
            a00 += __shfl_xor(a00, off, 64);
            a01 += __shfl_xor(a01, off, 64);
            a10 += __shfl_xor(a10, off, 64);
            a11 += __shfl_xor(a11, off, 64);
            c00 += __shfl_xor(c00, off, 64);
            c01 += __shfl_xor(c01, off, 64);
            c10 += __shfl_xor(c10, off, 64);
            c11 += __shfl_xor(c11, off, 64);
            e00 += __shfl_xor(e00, off, 64);
            e01 += __shfl_xor(e01, off, 64);
            e10 += __shfl_xor(e10, off, 64);
            e11 += __shfl_xor(e11, off, 64);
        }
        if (lane == 0) {
            g_P[r0    ] = make_float4(a00, a01, a10, a11);
            g_P[r0 + 1] = make_float4(c00, c01, c10, c11);
            g_P[r0 + 2] = make_float4(e00, e01, e10, e11);
        }
    }

    // ---- Grid barrier (manual, replay-safe) ----
    __syncthreads();
    if (threadIdx.x == 0) {
        __threadfence();  // release: this block's g_P stores visible agent-wide
        const unsigned old = atomicAdd(&g_ctr, 1u);           // device scope
        const unsigned target = (old & ~255u) + 256u;         // this round's goal
        int spins = 0;
        while (__hip_atomic_load(&g_ctr, __ATOMIC_RELAXED,
                                 __HIP_MEMORY_SCOPE_AGENT) < target) {
            if (++spins > (1 << 18)) break;  // ms-scale bailout: clean fail, no hang
            __builtin_amdgcn_s_sleep(2);
        }
        __threadfence();  // acquire: invalidate caches so g_P reads are fresh
    }
    __syncthreads();

    // ---- Phase 2: 256 pairs for this block (indices already in registers) ----
    if (ptid < PAIRS_PER_BLK) {
        const int t = blockIdx.x * PAIRS_PER_BLK + ptid;  // pair id = b*K + k
        const int i0 = min(max(id.x, 0), NN - 1);   // clamp: dtype surprise ->
        const int i1 = min(max(id.y, 0), NN - 1);   // absmax fail, not a fault
        const int b = t >> 10;  // K = 1024
        const float4 p0 = g_P[b * NN + i0];
        const float4 p1 = g_P[b * NN + i1];
        const float b0 = bh[0], b1 = bh[1];
        ((float2*)out)[t] = make_float2(p0.x + p1.z + b0, p0.y + p1.w + b1);
        ((float2*)out)[PAIRS + t] = make_float2((float)id.x, (float)id.y);
    }
}

extern "C" void kernel_launch(void* const* d_in, const int* in_sizes, int n_in,
                              void* d_out, int out_size, void* d_ws, size_t ws_size,
                              hipStream_t stream) {
    const float* z   = (const float*)d_in[0];
    const int*   idx = (const int*)d_in[1];
    const float* W   = (const float*)d_in[2];
    const float* bh  = (const float*)d_in[3];
    float*       out = (float*)d_out;
    (void)d_ws; (void)ws_size; (void)in_sizes; (void)n_in; (void)out_size;

    // 256 blocks = #CUs (manual-barrier residency), 16 waves each.
    partvit_onekernel<<<NBLK, TPB, 0, stream>>>(z, idx, W, bh, out);
}

// Round 4
// 187.243 us; speedup vs baseline: 1.0189x; 1.0039x over previous
//
#include <hip/hip_runtime.h>

// Problem constants (PARTViT pairwise head)
#define BB 64
#define NN 576
#define DD 768
#define KK 1024
#define ROWS (BB * NN)    // 36864 patch rows
#define PAIRS (BB * KK)   // 65536 pairs
// d_out layout: [PAIRS*2] f32 head output, then [PAIRS*2] f32 echoed indices
//
// R7: direct-gather, no P table, no barrier, no phases.
// R4-R6 post-mortem: all one-kernel phase variants pinned at ~69 us with
// VALUBusy 4%, HBM 11%, occupancy 21->41% irrelevant. Diagnosis: MLP-bound.
// Loads-in-flight/CU ~2-3 KB at ~500ns latency -> ~6 GB/s/CU, and each
// block runs ONCE per CU (zero churn) so the pipe drains and stays empty.
// Fix: embarrassingly-parallel form. out[p] = z[i0].W[:768] + z[i1].W[768:]
// + b computed per pair directly: 8192 blocks (32/CU churn), one wave per
// 2 pairs, 12 independent dwordx4 issued up front. Redundant FLOPs (~3.6x
// per row) are ~5 us of VALU - hidden under memory.
// XCD swizzle: round-robin dispatch sends block b to XCD b%8; remap so XCD
// x handles pair-groups [x*1024,(x+1)*1024) = batches [8x,8x+8). Per-batch
// gather working set = 576 rows * 3 KB = 1.77 MB < 4 MB per-XCD L2, so
// repeated row draws are L2 hits and chip-wide HBM/L3 demand stays ~= one
// full z read (113 MB). Swizzle is a locality heuristic only - any
// permutation is correct.

#define NBLK 8192
#define TPB  256
#define PPB  8           // pairs per block = 4 waves x 2

__global__ __launch_bounds__(TPB, 4)
void partvit_direct(const float* __restrict__ z,
                    const int* __restrict__ idx,
                    const float* __restrict__ W,
                    const float* __restrict__ bh,
                    float* __restrict__ out) {
    const int lane = threadIdx.x & 63;
    const int wv   = threadIdx.x >> 6;   // 0..3

    // pair-group swizzle (see header comment)
    const int g  = (blockIdx.x & 7) * (NBLK / 8) + (blockIdx.x >> 3);
    const int p0 = g * PPB + wv * 2;     // this wave's two pairs: p0, p0+1
    const int p1 = p0 + 1;

    // Pair indices (8 B each, wave-uniform broadcast load). Clamped so a
    // dtype-contract surprise yields a clean absmax failure, not a fault.
    const int2 id0 = ((const int2*)idx)[p0];
    const int2 id1 = ((const int2*)idx)[p1];
    const int bt  = p0 >> 10;            // batch; p0,p1 same batch (PPB | 1024)
    const int r00 = bt * NN + min(max(id0.x, 0), NN - 1);
    const int r01 = bt * NN + min(max(id0.y, 0), NN - 1);
    const int r10 = bt * NN + min(max(id1.x, 0), NN - 1);
    const int r11 = bt * NN + min(max(id1.y, 0), NN - 1);

    // Issue all 12 row loads (2 pairs x 2 rows x 3 float4) before any use:
    // ~12 dwordx4 in flight per wave; 16 resident waves/CU + 32-block churn
    // keep the CU's memory pipe full (the thing R4-R6 lacked).
    const float4* __restrict__ z4 = (const float4*)z;  // 192 float4 per row
    float4 u0[3], u1[3], u2[3], u3[3];
#pragma unroll
    for (int j = 0; j < 3; ++j) u0[j] = z4[r00 * 192 + j * 64 + lane];
#pragma unroll
    for (int j = 0; j < 3; ++j) u1[j] = z4[r01 * 192 + j * 64 + lane];
#pragma unroll
    for (int j = 0; j < 3; ++j) u2[j] = z4[r10 * 192 + j * 64 + lane];
#pragma unroll
    for (int j = 0; j < 3; ++j) u3[j] = z4[r11 * 192 + j * 64 + lane];

    // W is [1536,2] row-major: W[d,t] at 2*d+t -> float2 per d. Lane l owns
    // d = j*256 + 4l + c. Weight loads are L1-resident (12 KB) after the
    // first block on each CU; each float2 feeds 4 FMAs immediately.
    const float2* __restrict__ W2 = (const float2*)W;
    const float* f0 = (const float*)u0;  // element e = j*4+c
    const float* f1 = (const float*)u1;
    const float* f2 = (const float*)u2;
    const float* f3 = (const float*)u3;

    float s00 = 0.f, s01 = 0.f, s10 = 0.f, s11 = 0.f;
#pragma unroll
    for (int j = 0; j < 3; ++j) {
#pragma unroll
        for (int c = 0; c < 4; ++c) {
            const int d = j * 256 + (lane << 2) + c;
            const float2 wA = W2[d];        // first-half weights (patch-0 slot)
            const float2 wB = W2[d + DD];   // second-half weights (patch-1 slot)
            const int e = j * 4 + c;
            s00 = fmaf(f0[e], wA.x, s00);
            s00 = fmaf(f1[e], wB.x, s00);
            s01 = fmaf(f0[e], wA.y, s01);
            s01 = fmaf(f1[e], wB.y, s01);
            s10 = fmaf(f2[e], wA.x, s10);
            s10 = fmaf(f3[e], wB.x, s10);
            s11 = fmaf(f2[e], wA.y, s11);
            s11 = fmaf(f3[e], wB.y, s11);
        }
    }

    // 64-lane butterfly: afterwards every lane holds the full sums.
#pragma unroll
    for (int off = 32; off > 0; off >>= 1) {
        s00 += __shfl_xor(s00, off, 64);
        s01 += __shfl_xor(s01, off, 64);
        s10 += __shfl_xor(s10, off, 64);
        s11 += __shfl_xor(s11, off, 64);
    }

    const float b0 = bh[0], b1 = bh[1];
    if (lane == 0) {
        ((float2*)out)[p0] = make_float2(s00 + b0, s01 + b1);
    } else if (lane == 1) {
        ((float2*)out)[p1] = make_float2(s10 + b0, s11 + b1);
    } else if (lane == 2) {
        ((float2*)out)[PAIRS + p0] = make_float2((float)id0.x, (float)id0.y);
    } else if (lane == 3) {
        ((float2*)out)[PAIRS + p1] = make_float2((float)id1.x, (float)id1.y);
    }
}

extern "C" void kernel_launch(void* const* d_in, const int* in_sizes, int n_in,
                              void* d_out, int out_size, void* d_ws, size_t ws_size,
                              hipStream_t stream) {
    const float* z   = (const float*)d_in[0];
    const int*   idx = (const int*)d_in[1];
    const float* W   = (const float*)d_in[2];
    const float* bh  = (const float*)d_in[3];
    float*       out = (float*)d_out;
    (void)d_ws; (void)ws_size; (void)in_sizes; (void)n_in; (void)out_size;

    // 8192 blocks x 256 thr: 8 pairs/block, ~32 blocks/CU of churn.
    partvit_direct<<<NBLK, TPB, 0, stream>>>(z, idx, W, bh, out);
}

// Round 5
// 166.432 us; speedup vs baseline: 1.1463x; 1.1250x over previous
//
#include <hip/hip_runtime.h>

// Problem constants (PARTViT pairwise head)
#define BB 64
#define NN 576
#define DD 768
#define KK 1024
#define ROWS (BB * NN)    // 36864 patch rows
#define PAIRS (BB * KK)   // 65536 pairs
// d_out layout: [PAIRS*2] f32 head output, then [PAIRS*2] f32 echoed indices
//
// R8: back to the R0 two-kernel skeleton (best measured slice ~49 us; every
// one-kernel variant R4-R7 pinned at 65-70 us regardless of structure).
// Only change vs R0: K1's inner schedule. Diagnosis across R0-R7: a
// dependent stream (load -> FMA -> serial butterfly -> store) drains its
// outstanding loads during each ~400cy compute window; at loaded-latency
// (~2-3 us near peak BW) a CU needs ~60+ KB continuously in flight to
// stream at the ~25 GB/s/CU cap the fills/m13 reach. Fix:
//   - straight-line body (NO loop -> no rematerialization heuristic that
//     produced VGPR=40/52 weight-reload pathology in R5/R6),
//   - 4 rows per wave, ALL 12 dwordx4 (12 KB/wave) issued before any FMA;
//     compute on rows 0-1 overlaps rows 2-3 still in flight,
//   - 2304 blocks (9 blocks/CU churn): finished waves are replaced by fresh
//     ones that immediately issue 12 more loads -> outstanding never drains.
// K2 verbatim from R0 (proven, ~4-6 us, L2-resident gathers).

#define K1_BLOCKS 2304   // ROWS / (4 waves * 4 rows)
#define TPB 256

// Per-patch projection table: P[r] = { z[r]·W[:768,0], z[r]·W[:768,1],
//                                      z[r]·W[768:,0], z[r]·W[768:,1] }
// Static device global (576 KB); fully rewritten each launch (replay-safe).
__device__ float4 g_P[ROWS];

__device__ __forceinline__ float4 rowdot(const float4 v[3],
                                         const float2 wa[3][4],
                                         const float2 wb[3][4]) {
    float s0 = 0.f, s1 = 0.f, s2 = 0.f, s3 = 0.f;
#pragma unroll
    for (int j = 0; j < 3; ++j) {
        const float e0 = v[j].x, e1 = v[j].y, e2 = v[j].z, e3 = v[j].w;
        s0 = fmaf(e0, wa[j][0].x, s0);
        s0 = fmaf(e1, wa[j][1].x, s0);
        s0 = fmaf(e2, wa[j][2].x, s0);
        s0 = fmaf(e3, wa[j][3].x, s0);
        s1 = fmaf(e0, wa[j][0].y, s1);
        s1 = fmaf(e1, wa[j][1].y, s1);
        s1 = fmaf(e2, wa[j][2].y, s1);
        s1 = fmaf(e3, wa[j][3].y, s1);
        s2 = fmaf(e0, wb[j][0].x, s2);
        s2 = fmaf(e1, wb[j][1].x, s2);
        s2 = fmaf(e2, wb[j][2].x, s2);
        s2 = fmaf(e3, wb[j][3].x, s2);
        s3 = fmaf(e0, wb[j][0].y, s3);
        s3 = fmaf(e1, wb[j][1].y, s3);
        s3 = fmaf(e2, wb[j][2].y, s3);
        s3 = fmaf(e3, wb[j][3].y, s3);
    }
    return make_float4(s0, s1, s2, s3);
}

// Interleaved dual butterfly: 8 independent add chains, 6 steps.
__device__ __forceinline__ void bfly2(float4& p, float4& q) {
#pragma unroll
    for (int off = 32; off > 0; off >>= 1) {
        p.x += __shfl_xor(p.x, off, 64);
        q.x += __shfl_xor(q.x, off, 64);
        p.y += __shfl_xor(p.y, off, 64);
        q.y += __shfl_xor(q.y, off, 64);
        p.z += __shfl_xor(p.z, off, 64);
        q.z += __shfl_xor(q.z, off, 64);
        p.w += __shfl_xor(p.w, off, 64);
        q.w += __shfl_xor(q.w, off, 64);
    }
}

// Kernel 1: 4 rows per wave, straight-line, all loads up front.
__global__ __launch_bounds__(TPB, 4)
void partvit_proj(const float* __restrict__ z, const float* __restrict__ W) {
    const int lane = threadIdx.x & 63;
    const int wave = threadIdx.x >> 6;   // 0..3

    // This wave's 4 contiguous rows. 2304*4 waves * 4 rows = 36864 exactly.
    const int rbase = (blockIdx.x * 4 + wave) * 4;

    // Issue all 12 row-loads (12 KB per wave) before anything else.
    const float4* __restrict__ z4 = (const float4*)z;  // 192 float4 per row
    float4 v[4][3];
#pragma unroll
    for (int rr = 0; rr < 4; ++rr)
#pragma unroll
        for (int j = 0; j < 3; ++j)
            v[rr][j] = z4[(size_t)(rbase + rr) * 192 + j * 64 + lane];

    // W is [1536,2] row-major: W[d,t] at 2*d+t -> float2 per d.
    // Lane l owns d = j*256 + 4l + c (j=0..2, c=0..3) of each half.
    // Straight-line body: these 24 float2 loads are CSE'd once, L1-hit after
    // the first block on each CU, and overlap the z-load latency.
    const float2* __restrict__ W2 = (const float2*)W;
    float2 wa[3][4], wb[3][4];
#pragma unroll
    for (int j = 0; j < 3; ++j)
#pragma unroll
        for (int c = 0; c < 4; ++c) {
            const int d = j * 256 + (lane << 2) + c;
            wa[j][c] = W2[d];        // first-half weights (patch-0 slot)
            wb[j][c] = W2[d + DD];   // second-half weights (patch-1 slot)
        }

    // Rows 0,1 compute while rows 2,3 loads are still in flight.
    float4 p0 = rowdot(v[0], wa, wb);
    float4 p1 = rowdot(v[1], wa, wb);
    bfly2(p0, p1);
    if (lane == 0)      g_P[rbase + 0] = p0;
    else if (lane == 1) g_P[rbase + 1] = p1;

    float4 p2 = rowdot(v[2], wa, wb);
    float4 p3 = rowdot(v[3], wa, wb);
    bfly2(p2, p3);
    if (lane == 0)      g_P[rbase + 2] = p2;
    else if (lane == 1) g_P[rbase + 3] = p3;
}

// Kernel 2 (verbatim R0): out = P[i0].xy + P[i1].zw + bias ; echo indices.
// Indices clamped to [0, NN-1] so a dtype-contract surprise yields a clean
// absmax failure instead of a memory fault.
__global__ __launch_bounds__(TPB) void partvit_pairs(const int* __restrict__ idx,
                                                     const float* __restrict__ bh,
                                                     float* __restrict__ out) {
    const int t = blockIdx.x * blockDim.x + threadIdx.x;  // pair id = b*K + k
    if (t >= PAIRS) return;
    const int2 id = ((const int2*)idx)[t];
    const int i0 = min(max(id.x, 0), NN - 1);
    const int i1 = min(max(id.y, 0), NN - 1);
    const int b = t >> 10;  // K = 1024
    const float4 p0 = g_P[b * NN + i0];
    const float4 p1 = g_P[b * NN + i1];
    const float b0 = bh[0], b1 = bh[1];
    ((float2*)out)[t] = make_float2(p0.x + p1.z + b0, p0.y + p1.w + b1);
    ((float2*)out)[PAIRS + t] = make_float2((float)id.x, (float)id.y);
}

extern "C" void kernel_launch(void* const* d_in, const int* in_sizes, int n_in,
                              void* d_out, int out_size, void* d_ws, size_t ws_size,
                              hipStream_t stream) {
    const float* z   = (const float*)d_in[0];
    const int*   idx = (const int*)d_in[1];
    const float* W   = (const float*)d_in[2];
    const float* bh  = (const float*)d_in[3];
    float*       out = (float*)d_out;
    (void)d_ws; (void)ws_size; (void)in_sizes; (void)n_in; (void)out_size;

    // K1: 2304 blocks * 4 waves, 4 rows/wave, ~9 blocks/CU churn.
    partvit_proj<<<K1_BLOCKS, TPB, 0, stream>>>(z, W);
    // K2: one thread per pair.
    partvit_pairs<<<PAIRS / TPB, TPB, 0, stream>>>(idx, bh, out);
}